// Round 11
// baseline (46.349 us; speedup 1.0000x reference)
//
#include <hip/hip_runtime.h>
#include <math.h>

// ---- DCT constants (fp32) ----
#define A0c 0.35355339059327373f
#define C1c 0.4903926402016152f
#define C2c 0.46193976625564337f
#define C3c 0.41573480615127262f
#define C5c 0.27778511650980114f
#define C6c 0.19134171618254492f
#define C7c 0.09754516100806417f

#define IMG_W 512
#define IMG_HW (512 * 512)

typedef float f8v __attribute__((ext_vector_type(8)));

// TRANSPOSED base JPEG tables: QT[v*8+u] = Q[u][v]. QUALITY=50 -> scaled==base.
__device__ const float QLUMT[64] = {
    16,12,14,14,18,24,49,72,
    11,12,13,17,22,35,64,92,
    10,14,16,22,37,55,78,95,
    16,19,24,29,56,64,87,98,
    24,26,40,51,68,81,103,112,
    40,58,57,87,109,104,121,100,
    51,60,69,80,103,113,120,103,
    61,55,56,62,77,92,101,99};
__device__ const float QCHRT[64] = {   // QCHR is symmetric
    17,18,24,47,99,99,99,99,
    18,21,26,66,99,99,99,99,
    24,26,56,99,99,99,99,99,
    47,66,99,99,99,99,99,99,
    99,99,99,99,99,99,99,99,
    99,99,99,99,99,99,99,99,
    99,99,99,99,99,99,99,99,
    99,99,99,99,99,99,99,99};

// In-place 8-point DCT-II
__device__ __forceinline__ void fdct8(float v[8]) {
    float s0 = v[0] + v[7], s1 = v[1] + v[6], s2 = v[2] + v[5], s3 = v[3] + v[4];
    float d0 = v[0] - v[7], d1 = v[1] - v[6], d2 = v[2] - v[5], d3 = v[3] - v[4];
    float e0 = s0 + s3, e1 = s1 + s2, f0 = s0 - s3, f1 = s1 - s2;
    v[0] = A0c * (e0 + e1);
    v[4] = A0c * (e0 - e1);
    v[2] = C2c * f0 + C6c * f1;
    v[6] = C6c * f0 - C2c * f1;
    v[1] = C1c * d0 + C3c * d1 + C5c * d2 + C7c * d3;
    v[3] = C3c * d0 - C7c * d1 - C1c * d2 - C5c * d3;
    v[5] = C5c * d0 - C1c * d1 + C7c * d2 + C3c * d3;
    v[7] = C7c * d0 - C5c * d1 + C3c * d2 - C1c * d3;
}

// In-place 8-point inverse
__device__ __forceinline__ void idct8(float v[8]) {
    float g0 = v[0], g1 = v[1], g2 = v[2], g3 = v[3];
    float g4 = v[4], g5 = v[5], g6 = v[6], g7 = v[7];
    float ep = A0c * (g0 + g4), em = A0c * (g0 - g4);
    float t26a = C2c * g2 + C6c * g6;
    float t26b = C6c * g2 - C2c * g6;
    float e0 = ep + t26a, e1 = em + t26b, e2 = em - t26b, e3 = ep - t26a;
    float o0 = C1c * g1 + C3c * g3 + C5c * g5 + C7c * g7;
    float o1 = C3c * g1 - C7c * g3 - C1c * g5 - C5c * g7;
    float o2 = C5c * g1 - C1c * g3 + C7c * g5 + C3c * g7;
    float o3 = C7c * g1 - C5c * g3 + C3c * g5 - C1c * g7;
    v[0] = e0 + o0; v[7] = e0 - o0;
    v[1] = e1 + o1; v[6] = e1 - o1;
    v[2] = e2 + o2; v[5] = e2 - o2;
    v[3] = e3 + o3; v[4] = e3 - o3;
}

// soft quantize-dequantize, symmetric tanh (no abs/copysign):
// tanh(15t) = (e2-1)/(e2+1), e2 = 2^(30*log2(e)*t); t in [-0.5,0.5] so
// exponent in [-21.7, 21.7] -> no overflow.
#define K_EXP2 43.2808512266689f
__device__ __forceinline__ float softq(float x, float q, float rq) {
    float d = x * rq;
    float rn = rintf(d);                   // nearest-even, matches jnp.round
    float t = d - rn;
    float e2 = __builtin_amdgcn_exp2f(K_EXP2 * t);  // v_exp_f32 = 2^x
    float th = (e2 - 1.0f) * __builtin_amdgcn_rcpf(e2 + 1.0f);
    return (d + 0.5f * th) * q;
}

// ---- in-register 8x8 transpose across the 8-lane group (lane bits 0..2) ----
template <int CTRL>
__device__ __forceinline__ float fdpp(float x) {
    return __int_as_float(__builtin_amdgcn_mov_dpp(__float_as_int(x), CTRL, 0xF, 0xF, false));
}
__device__ __forceinline__ float fswz4(float x) {   // lane ^= 4 (BitMode xor)
    return __int_as_float(__builtin_amdgcn_ds_swizzle(__float_as_int(x), 0x101F));
}

// lane holds row r (= lane&7) of an 8x8 matrix in v[0..7]; after call, lane
// holds column r. Butterfly: swap lane-bit k with reg-bit k, k = 0,1,2.
// new[i] = (r_k == i_k) ? cur[i] : shfl_xor_k(cur[i ^ (1<<k)])
__device__ __forceinline__ void xpose8(float v[8], bool rb0, bool rb1, bool rb2) {
    float t[8];
    // stage 0: lane^1 = quad_perm [1,0,3,2] = 0xB1
#pragma unroll
    for (int i = 0; i < 8; ++i) t[i] = fdpp<0xB1>(v[i ^ 1]);
#pragma unroll
    for (int i = 0; i < 8; ++i) v[i] = (((i & 1) != 0) == rb0) ? v[i] : t[i];
    // stage 1: lane^2 = quad_perm [2,3,0,1] = 0x4E
#pragma unroll
    for (int i = 0; i < 8; ++i) t[i] = fdpp<0x4E>(v[i ^ 2]);
#pragma unroll
    for (int i = 0; i < 8; ++i) v[i] = (((i & 2) != 0) == rb1) ? v[i] : t[i];
    // stage 2: lane^4 = ds_swizzle xor-4
#pragma unroll
    for (int i = 0; i < 8; ++i) t[i] = fswz4(v[i ^ 4]);
#pragma unroll
    for (int i = 0; i < 8; ++i) v[i] = (((i & 4) != 0) == rb2) ? v[i] : t[i];
}

// One wave = one 64x8 tile, all 3 channels, ZERO LDS, zero __syncthreads.
// lane = blk*8 + row so transpose partners are lane-bits 0..2 (DPP/swizzle).
__global__ __launch_bounds__(256) void jpeg_kernel(const float* __restrict__ x,
                                                   float* __restrict__ out) {
    const int tid = threadIdx.x;
    const int wid = tid >> 6;
    const int lane = tid & 63;

    const int gw = blockIdx.x * 4 + wid;     // 0..16383
    const int bimg = gw >> 9;                // image
    const int rem = gw & 511;
    const int gh = rem >> 3;                 // 8-row strip index
    const int tx = rem & 7;                  // 64-col tile index

    const int r = lane & 7;                  // row within strip / freq v
    const int blk = lane >> 3;               // 8x8 block within tile

    const bool rb0 = (r & 1) != 0, rb1 = (r & 2) != 0, rb2 = (r & 4) != 0;

    const size_t off = (size_t)bimg * 3 * IMG_HW +
                       (size_t)(gh * 8 + r) * IMG_W + tx * 64 + blk * 8;
    const float* base = x + off;

    const f8v Rv = *(const f8v*)(base);
    const f8v Gv = *(const f8v*)(base + IMG_HW);
    const f8v Bv = *(const f8v*)(base + 2 * IMG_HW);

    const f8v qL = *(const f8v*)&QLUMT[r * 8];
    const f8v qC = *(const f8v*)&QCHRT[r * 8];
    f8v rqL, rqC;
#pragma unroll
    for (int u = 0; u < 8; ++u) {
        rqL[u] = __builtin_amdgcn_rcpf(qL[u]);
        rqC[u] = __builtin_amdgcn_rcpf(qC[u]);
    }

    // ---- forward color (all channels, in regs) ----
    float g0[8], g1[8], g2[8];
#pragma unroll
    for (int k = 0; k < 8; ++k) {
        float R = Rv[k], G = Gv[k], B = Bv[k];
        g0[k] = 0.299f * R + 0.587f * G + 0.114f * B - 0.5f;
        g1[k] = -0.168736f * R - 0.331264f * G + 0.5f * B;
        g2[k] = 0.5f * R - 0.418688f * G - 0.081312f * B;
    }

    // ---- per-channel: H-DCT, xpose, V-DCT, softq, V-iDCT, xpose, H-iDCT ----
    // All register ops; compiler freely interleaves the three channels.
    fdct8(g0);
    xpose8(g0, rb0, rb1, rb2);
    fdct8(g0);
#pragma unroll
    for (int u = 0; u < 8; ++u) g0[u] = softq(g0[u], qL[u], rqL[u]);
    idct8(g0);
    xpose8(g0, rb0, rb1, rb2);
    idct8(g0);

    fdct8(g1);
    xpose8(g1, rb0, rb1, rb2);
    fdct8(g1);
#pragma unroll
    for (int u = 0; u < 8; ++u) g1[u] = softq(g1[u], qC[u], rqC[u]);
    idct8(g1);
    xpose8(g1, rb0, rb1, rb2);
    idct8(g1);

    fdct8(g2);
    xpose8(g2, rb0, rb1, rb2);
    fdct8(g2);
#pragma unroll
    for (int u = 0; u < 8; ++u) g2[u] = softq(g2[u], qC[u], rqC[u]);
    idct8(g2);
    xpose8(g2, rb0, rb1, rb2);
    idct8(g2);

    // ---- inverse color + coalesced stores ----
    f8v Ro, Go, Bo;
#pragma unroll
    for (int k = 0; k < 8; ++k) {
        float Y  = g0[k] + 0.5f;
        float Cb = g1[k];
        float Cr = g2[k];
        float R = Y + 1.402f * Cr;
        float G = Y - 0.344136f * Cb - 0.714136f * Cr;
        float B = Y + 1.772f * Cb;
        Ro[k] = fminf(fmaxf(R, 0.0f), 1.0f);
        Go[k] = fminf(fmaxf(G, 0.0f), 1.0f);
        Bo[k] = fminf(fmaxf(B, 0.0f), 1.0f);
    }
    float* obase = out + off;
    *(f8v*)(obase) = Ro;
    *(f8v*)(obase + IMG_HW) = Go;
    *(f8v*)(obase + 2 * IMG_HW) = Bo;
}

extern "C" void kernel_launch(void* const* d_in, const int* in_sizes, int n_in,
                              void* d_out, int out_size, void* d_ws, size_t ws_size,
                              hipStream_t stream) {
    const float* x = (const float*)d_in[0];
    float* out = (float*)d_out;
    const int B = in_sizes[0] / (3 * IMG_HW);   // 32
    const int n_wg = B * 128;                   // B*512 tiles, 4 waves/WG
    hipLaunchKernelGGL(jpeg_kernel, dim3(n_wg), dim3(256), 0, stream, x, out);
}